// Round 1
// baseline (1731.936 us; speedup 1.0000x reference)
//
#include <hip/hip_runtime.h>

// ---------------------------------------------------------------------------
// out[b,t,f] = sum_d x[b,t,d] * (W[d,f] / scale[f])
// GEMM: M=8192 (B*T), K=4096 (D), N=16384 (F)
// Path: x -> bf16 (ws), W int -> bf16 W^T (ws), m97-structure bf16 MFMA GEMM
// with 1/scale epilogue. Threshold is 2% relative -> bf16 is safe (int8 exact
// in bf16; x rounding error ~2^-9 * sqrt(K)).
// ws layout: [0, 64MiB) Xbf ; [64MiB, 192MiB) WTbf. Requires ws >= 192 MiB.
// ---------------------------------------------------------------------------

namespace {

constexpr int MD = 8192;    // B*T
constexpr int ND = 16384;   // F
constexpr int KD = 4096;    // D

typedef __bf16 bf16x8 __attribute__((ext_vector_type(8)));
typedef float  f32x4  __attribute__((ext_vector_type(4)));
typedef float  fl4    __attribute__((ext_vector_type(4)));
typedef unsigned int u32x4 __attribute__((ext_vector_type(4)));

__device__ __forceinline__ unsigned int f2bf(float f) {
  // round-to-nearest-even fp32 -> bf16 (as uint16 in low bits)
  unsigned int u = __float_as_uint(f);
  return (u + 0x7FFFu + ((u >> 16) & 1u)) >> 16;
}

// ---- x fp32 [M][K] -> bf16 [M][K] ----------------------------------------
__global__ __launch_bounds__(256) void convert_x_kernel(
    const float* __restrict__ x, unsigned short* __restrict__ xb) {
  size_t i = ((size_t)blockIdx.x * 256 + threadIdx.x) * 8;
  fl4 a = *(const fl4*)(x + i);
  fl4 b = *(const fl4*)(x + i + 4);
  u32x4 o;
  o.x = f2bf(a.x) | (f2bf(a.y) << 16);
  o.y = f2bf(a.z) | (f2bf(a.w) << 16);
  o.z = f2bf(b.x) | (f2bf(b.y) << 16);
  o.w = f2bf(b.z) | (f2bf(b.w) << 16);
  *(u32x4*)(xb + i) = o;
}

// ---- W int32 [K][N] -> bf16 W^T [N][K] ------------------------------------
// Each thread owns one column n and a 64-deep k-strip: reads are coalesced
// across lanes (consecutive n), writes are a contiguous 128B chunk per thread.
__global__ __launch_bounds__(256) void transpose_w_kernel(
    const int* __restrict__ W, unsigned short* __restrict__ WT) {
  constexpr int KC = 64;
  const int nb = blockIdx.x & 63;   // N/256 = 64 blocks along n
  const int kb = blockIdx.x >> 6;   // K/KC  = 64 chunks along k
  const int n  = nb * 256 + threadIdx.x;
  const int k0 = kb * KC;

  unsigned int buf[KC / 2];
  const int* src = W + (size_t)k0 * ND + n;
#pragma unroll
  for (int i = 0; i < KC; i += 2) {
    int v0 = src[(size_t)i * ND];
    int v1 = src[(size_t)(i + 1) * ND];
    buf[i >> 1] = f2bf((float)v0) | (f2bf((float)v1) << 16);
  }
  u32x4* dst = (u32x4*)(WT + (size_t)n * KD + k0);
#pragma unroll
  for (int j = 0; j < KC / 8; ++j) {
    u32x4 o;
    o.x = buf[4 * j + 0];
    o.y = buf[4 * j + 1];
    o.z = buf[4 * j + 2];
    o.w = buf[4 * j + 3];
    dst[j] = o;
  }
}

// ---- m97-structure GEMM ---------------------------------------------------
// C[M][N] = Abf[M][K] * WT[N][K]^T, epilogue * (1/scale[col])
// 128x128 tile, BK=32, 4 waves (2x2), each wave 64x64 = 4x4 frags of 16x16.

#define GLL16(g, l)                                                  \
  __builtin_amdgcn_global_load_lds(                                  \
      (const __attribute__((address_space(1))) void*)(g),            \
      (__attribute__((address_space(3))) void*)(l), 16, 0, 0)

__global__ __launch_bounds__(256) void gemm_kernel(
    const unsigned short* __restrict__ A,   // bf16 [M][K]
    const unsigned short* __restrict__ Bt,  // bf16 [N][K]
    const float* __restrict__ scale,        // [N]
    float* __restrict__ C) {                // f32 [M][N]
  __shared__ __align__(16) unsigned short Alds[128 * 32];
  __shared__ __align__(16) unsigned short Blds[128 * 32];

  const int tid  = threadIdx.x;
  const int lane = tid & 63;
  const int w    = tid >> 6;  // wave 0..3
  const int wm   = w >> 1;    // wave row (0..1)
  const int wn   = w & 1;     // wave col (0..1)

  // XCD-aware bijective swizzle (nwg = 8192, divisible by 8)
  const int ntn = ND / 128;              // 128 tiles along n
  const int nwg = (MD / 128) * ntn;      // 8192
  const int cpx = nwg >> 3;
  const int bid = blockIdx.x;
  const int swz = (bid & 7) * cpx + (bid >> 3);
  const int tm  = swz / ntn;
  const int tn  = swz % ntn;
  const size_t brow = (size_t)tm * 128;
  const size_t bcol = (size_t)tn * 128;

  f32x4 acc[4][4];
  const f32x4 z = {0.f, 0.f, 0.f, 0.f};
#pragma unroll
  for (int i = 0; i < 4; ++i)
#pragma unroll
    for (int j = 0; j < 4; ++j) acc[i][j] = z;

  // staging addressing: wave w stages rows [32w, 32w+32) of both tiles,
  // 2 issues x 16 rows; lane covers row = base + lane/4, k-bytes (lane&3)*16
  const int srow = w << 5;
  const int lrow = lane >> 2;
  const int lk8  = (lane & 3) << 3;

  const unsigned short* Ag0 = A  + (brow + srow + lrow) * (size_t)KD + lk8;
  const unsigned short* Bg0 = Bt + (bcol + srow + lrow) * (size_t)KD + lk8;
  char* Al0 = (char*)Alds + srow * 64;  // wave-uniform LDS base (64 B rows)
  char* Bl0 = (char*)Blds + srow * 64;

  // per-lane fragment read bases: row = (lane&15), k-chunk = (lane>>4)*8 elems
  const char* abase = (const char*)Alds + (lane & 15) * 64 + ((lane >> 4) << 4);
  const char* bbase = (const char*)Blds + (lane & 15) * 64 + ((lane >> 4) << 4);

  for (int kt = 0; kt < KD; kt += 32) {
    GLL16(Ag0 + kt,               Al0);
    GLL16(Ag0 + (size_t)16 * KD + kt, Al0 + 16 * 64);
    GLL16(Bg0 + kt,               Bl0);
    GLL16(Bg0 + (size_t)16 * KD + kt, Bl0 + 16 * 64);
    __syncthreads();

    bf16x8 af[4], bfr[4];
#pragma unroll
    for (int mi = 0; mi < 4; ++mi)
      af[mi] = *(const bf16x8*)(abase + (wm * 64 + mi * 16) * 64);
#pragma unroll
    for (int ni = 0; ni < 4; ++ni)
      bfr[ni] = *(const bf16x8*)(bbase + (wn * 64 + ni * 16) * 64);

#pragma unroll
    for (int mi = 0; mi < 4; ++mi)
#pragma unroll
      for (int ni = 0; ni < 4; ++ni)
        acc[mi][ni] = __builtin_amdgcn_mfma_f32_16x16x32_bf16(
            af[mi], bfr[ni], acc[mi][ni], 0, 0, 0);
    __syncthreads();
  }

  // epilogue: C/D layout col = lane&15, row = (lane>>4)*4 + r
#pragma unroll
  for (int ni = 0; ni < 4; ++ni) {
    const size_t col = bcol + wn * 64 + ni * 16 + (lane & 15);
    const float inv = 1.0f / scale[col];
#pragma unroll
    for (int mi = 0; mi < 4; ++mi) {
      const size_t row = brow + wm * 64 + mi * 16 + ((lane >> 4) << 2);
      float* cp = C + row * ND + col;
#pragma unroll
      for (int r = 0; r < 4; ++r)
        cp[(size_t)r * ND] = acc[mi][ni][r] * inv;
    }
  }
}

}  // namespace

extern "C" void kernel_launch(void* const* d_in, const int* in_sizes, int n_in,
                              void* d_out, int out_size, void* d_ws,
                              size_t ws_size, hipStream_t stream) {
  const float* x     = (const float*)d_in[0];
  const int*   W     = (const int*)d_in[1];
  const float* scale = (const float*)d_in[2];
  float*       out   = (float*)d_out;

  unsigned short* xb = (unsigned short*)d_ws;                            // 64 MiB
  unsigned short* wt = (unsigned short*)((char*)d_ws + (size_t)MD * KD * 2);  // 128 MiB

  // x fp32 -> bf16: 33.5M elems / 8 per thread / 256 = 16384 blocks
  convert_x_kernel<<<16384, 256, 0, stream>>>(x, xb);
  // W int [K][N] -> bf16 [N][K]: (N/256) * (K/64) = 4096 blocks
  transpose_w_kernel<<<4096, 256, 0, stream>>>(W, wt);
  // GEMM: (M/128) * (N/128) = 8192 blocks
  gemm_kernel<<<8192, 256, 0, stream>>>(xb, wt, scale, out);
}

// Round 2
// 1534.504 us; speedup vs baseline: 1.1287x; 1.1287x over previous
//
#include <hip/hip_runtime.h>

// ---------------------------------------------------------------------------
// out[b,t,f] = sum_d x[b,t,d] * (W[d,f] / scale[f])
// GEMM: M=8192 (B*T), K=4096 (D), N=16384 (F)
// Pipeline: x->bf16 (ws), W int -> bf16 W^T (ws), then 256x256-tile 8-phase
// deep-pipelined bf16 MFMA GEMM (T2 LDS swizzle + T3/T4 counted vmcnt + T5
// setprio), 1/scale epilogue. ws: [0,64MiB) Xbf, [64MiB,192MiB) WTbf.
// ---------------------------------------------------------------------------

namespace {

constexpr int MD = 8192;    // B*T
constexpr int ND = 16384;   // F
constexpr int KD = 4096;    // D
constexpr int NT = KD / 64; // 64 k-tiles of BK=64

typedef __bf16 bf16x8 __attribute__((ext_vector_type(8)));
typedef float  f32x4  __attribute__((ext_vector_type(4)));
typedef float  fl4    __attribute__((ext_vector_type(4)));
typedef unsigned int u32x4 __attribute__((ext_vector_type(4)));

__device__ __forceinline__ unsigned int f2bf(float f) {
  unsigned int u = __float_as_uint(f);
  return (u + 0x7FFFu + ((u >> 16) & 1u)) >> 16;
}

// ---- x fp32 [M][K] -> bf16 [M][K] ----------------------------------------
__global__ __launch_bounds__(256) void convert_x_kernel(
    const float* __restrict__ x, unsigned short* __restrict__ xb) {
  size_t i = ((size_t)blockIdx.x * 256 + threadIdx.x) * 8;
  fl4 a = *(const fl4*)(x + i);
  fl4 b = *(const fl4*)(x + i + 4);
  u32x4 o;
  o.x = f2bf(a.x) | (f2bf(a.y) << 16);
  o.y = f2bf(a.z) | (f2bf(a.w) << 16);
  o.z = f2bf(b.x) | (f2bf(b.y) << 16);
  o.w = f2bf(b.z) | (f2bf(b.w) << 16);
  *(u32x4*)(xb + i) = o;
}

// ---- W int32 [K][N] -> bf16 W^T [N][K] ------------------------------------
__global__ __launch_bounds__(256) void transpose_w_kernel(
    const int* __restrict__ W, unsigned short* __restrict__ WT) {
  constexpr int KC = 64;
  const int nb = blockIdx.x & 63;
  const int kb = blockIdx.x >> 6;
  const int n  = nb * 256 + threadIdx.x;
  const int k0 = kb * KC;

  unsigned int buf[KC / 2];
  const int* src = W + (size_t)k0 * ND + n;
#pragma unroll
  for (int i = 0; i < KC; i += 2) {
    int v0 = src[(size_t)i * ND];
    int v1 = src[(size_t)(i + 1) * ND];
    buf[i >> 1] = f2bf((float)v0) | (f2bf((float)v1) << 16);
  }
  u32x4* dst = (u32x4*)(WT + (size_t)n * KD + k0);
#pragma unroll
  for (int j = 0; j < KC / 8; ++j) {
    u32x4 o;
    o.x = buf[4 * j + 0];
    o.y = buf[4 * j + 1];
    o.z = buf[4 * j + 2];
    o.w = buf[4 * j + 3];
    dst[j] = o;
  }
}

// ---- 256x256 8-phase GEMM -------------------------------------------------

#define GLL16(g, l)                                                  \
  __builtin_amdgcn_global_load_lds(                                  \
      (const __attribute__((address_space(1))) void*)(g),            \
      (__attribute__((address_space(3))) void*)(l), 16, 0, 0)

#define BAR()        asm volatile("s_barrier" ::: "memory")
#define WAIT_LGKM0() asm volatile("s_waitcnt lgkmcnt(0)" ::: "memory")
#define WAIT_VM4()   asm volatile("s_waitcnt vmcnt(4)" ::: "memory")
#define PRIO1()      __builtin_amdgcn_s_setprio(1)
#define PRIO0()      __builtin_amdgcn_s_setprio(0)

// one "half-tile" = 128 rows x 64 bf16 (16 KB) = 2 global_load_lds per wave.
// LDS dest is linear; source col is pre-swizzled (rule #21) so that
// LDS[row][col'] = G[row][col' ^ ((row&7)<<4 bytes)].
__device__ __forceinline__ void stage_half(const unsigned short* g0,
                                           unsigned short* lbase, int w) {
  char* l = (char*)lbase + w * 1024;
  GLL16(g0, l);
  GLL16(g0 + (size_t)64 * KD, l + 8192);
}

// ds_read of one MFMA A/B fragment with the read-side swizzle
#define RD_A(DST, MOFF)                                                       \
  _Pragma("unroll") for (int mi = 0; mi < 4; ++mi)                            \
  _Pragma("unroll") for (int kk = 0; kk < 2; ++kk)                            \
      DST[mi][kk] = *(const bf16x8*)(Ard + (size_t)((MOFF + mi) * 16 + r15) * \
                                               128 +                          \
                                     ((kk * 64 + hi16) ^ sw16));

#define RD_B(DST, NOFF)                                                       \
  _Pragma("unroll") for (int ni = 0; ni < 2; ++ni)                            \
  _Pragma("unroll") for (int kk = 0; kk < 2; ++kk)                            \
      DST[ni][kk] = *(const bf16x8*)(Brd + (size_t)((NOFF + ni) * 16 + r15) * \
                                               128 +                          \
                                     ((kk * 64 + hi16) ^ sw16));

#define QUAD(AARR, BARR, MB, NB)                                              \
  _Pragma("unroll") for (int mi = 0; mi < 4; ++mi)                            \
  _Pragma("unroll") for (int ni = 0; ni < 2; ++ni)                            \
  _Pragma("unroll") for (int kk = 0; kk < 2; ++kk)                            \
      acc[MB + mi][NB + ni] = __builtin_amdgcn_mfma_f32_16x16x32_bf16(        \
          AARR[mi][kk], BARR[ni][kk], acc[MB + mi][NB + ni], 0, 0, 0);

__global__ __launch_bounds__(512, 2) void gemm_kernel(
    const unsigned short* __restrict__ A,   // bf16 [M][K]
    const unsigned short* __restrict__ Bt,  // bf16 [N][K]
    const float* __restrict__ scale,        // [N]
    float* __restrict__ C) {                // f32 [M][N]
  // [buf][256 rows][64 bf16]; half0 = rows 0-127 (8192 elems), half1 = rows 128-255
  __shared__ __align__(16) unsigned short Asmem[2][16384];
  __shared__ __align__(16) unsigned short Bsmem[2][16384];

  const int tid  = threadIdx.x;
  const int lane = tid & 63;
  const int w    = tid >> 6;   // wave 0..7
  const int wm   = w >> 2;     // 0..1 : owns A rows wm*128..+127
  const int wn   = w & 3;      // 0..3 : owns B cols wn*64..+63

  // grid swizzle: per-XCD chunks are tn-major (each XCD owns 8 exclusive
  // B-panel columns and sweeps all tm) -> B read once chip-wide, A L3-hits.
  const int bid = blockIdx.x;               // 2048 blocks (32 tm x 64 tn)
  const int swz = (bid & 7) * 256 + (bid >> 3);
  const int tm  = swz & 31;
  const int tn  = swz >> 5;
  const size_t brow = (size_t)tm * 256;
  const size_t bcol = (size_t)tn * 256;

  // staging source addressing (pre-swizzled col, see stage_half)
  const int srow = w * 8 + (lane >> 3);                        // 0..63
  const int scol = (((lane & 7) ^ ((lane >> 3) & 7)) << 3);    // elems
  const unsigned short* Ag = A  + (brow + srow) * (size_t)KD + scol;
  const unsigned short* Bg = Bt + (bcol + srow) * (size_t)KD + scol;

  // fragment-read addressing
  const int r15  = lane & 15;
  const int hi16 = (lane >> 4) << 4;   // byte col within row
  const int sw16 = (lane & 7) << 4;    // read-side swizzle XOR

  f32x4 acc[8][4];
  const f32x4 z = {0.f, 0.f, 0.f, 0.f};
#pragma unroll
  for (int i = 0; i < 8; ++i)
#pragma unroll
    for (int j = 0; j < 4; ++j) acc[i][j] = z;

  // ---- prologue: tile0 (A0,A1,B0,B1 -> buf0), tile1 (A0,A1 -> buf1) ----
  stage_half(Ag,                      &Asmem[0][0],    w);
  stage_half(Ag + (size_t)128 * KD,   &Asmem[0][8192], w);
  stage_half(Bg,                      &Bsmem[0][0],    w);
  stage_half(Bg + (size_t)128 * KD,   &Bsmem[0][8192], w);
  stage_half(Ag + 64,                 &Asmem[1][0],    w);
  stage_half(Ag + (size_t)128 * KD + 64, &Asmem[1][8192], w);
  WAIT_VM4();  // tile0 fully resident (newest 4 loads = tile1 A halves)
  BAR();

  bf16x8 aL[4][2], aH[4][2], bL[2][2], bH[2][2];

  // ---- main loop: 32 iters x 2 K-tiles, 8 phases/iter ----
  for (int it = 0; it < NT / 2; ++it) {
    const int T = 2 * it;
#pragma unroll
    for (int h = 0; h < 2; ++h) {
      const char* Ard = (const char*)&Asmem[h][0] + wm * 16384;
      const char* Brd =
          (const char*)&Bsmem[h][0] + (wn >> 1) * 16384 + (wn & 1) * 64 * 128;
      const size_t kbB = (size_t)((T + 1 + h) & (NT - 1)) * 64;
      const size_t kbA = (size_t)((T + 2 + h) & (NT - 1)) * 64;
      unsigned short* Bdst = &Bsmem[h ^ 1][0];
      unsigned short* Adst = &Asmem[h][0];

      // PH1: reads A m0-3 + B n0-1 ; stage next B half0
      RD_A(aL, 0);
      RD_B(bL, 0);
      stage_half(Bg + kbB, Bdst, w);
      BAR();
      WAIT_LGKM0();
      PRIO1();
      QUAD(aL, bL, 0, 0);
      PRIO0();
      BAR();

      // PH2: reads A m4-7 + B n2-3 ; stage next B half1
      // (all reads of buf h complete after this phase's trailing barrier)
      RD_A(aH, 4);
      RD_B(bH, 2);
      stage_half(Bg + (size_t)128 * KD + kbB, Bdst + 8192, w);
      BAR();
      WAIT_LGKM0();
      PRIO1();
      QUAD(aL, bH, 0, 2);
      PRIO0();
      BAR();

      // PH3: stage next-next A half0 (safe: buf h reads certified at PH2 bar)
      stage_half(Ag + kbA, Adst, w);
      BAR();
      PRIO1();
      QUAD(aH, bL, 4, 0);
      PRIO0();
      BAR();

      // PH4: stage next-next A half1 ; counted vmcnt certifies next tile
      stage_half(Ag + (size_t)128 * KD + kbA, Adst + 8192, w);
      BAR();
      PRIO1();
      QUAD(aH, bH, 4, 2);
      PRIO0();
      WAIT_VM4();  // newest 4 = this half's A stages; everything older done
      BAR();
    }
  }

  // ---- epilogue: acc * (1/scale[col]) -> C ----
  const int r4 = (lane >> 4) << 2;
#pragma unroll
  for (int ni = 0; ni < 4; ++ni) {
    const size_t col = bcol + wn * 64 + ni * 16 + r15;
    const float inv = 1.0f / scale[col];
#pragma unroll
    for (int mi = 0; mi < 8; ++mi) {
      float* cp = C + (brow + wm * 128 + mi * 16 + r4) * (size_t)ND + col;
#pragma unroll
      for (int r = 0; r < 4; ++r) cp[(size_t)r * ND] = acc[mi][ni][r] * inv;
    }
  }
}

}  // namespace

extern "C" void kernel_launch(void* const* d_in, const int* in_sizes, int n_in,
                              void* d_out, int out_size, void* d_ws,
                              size_t ws_size, hipStream_t stream) {
  const float* x     = (const float*)d_in[0];
  const int*   W     = (const int*)d_in[1];
  const float* scale = (const float*)d_in[2];
  float*       out   = (float*)d_out;

  unsigned short* xb = (unsigned short*)d_ws;
  unsigned short* wt = (unsigned short*)((char*)d_ws + (size_t)MD * KD * 2);

  convert_x_kernel<<<16384, 256, 0, stream>>>(x, xb);
  transpose_w_kernel<<<4096, 256, 0, stream>>>(W, wt);
  gemm_kernel<<<2048, 512, 0, stream>>>(xb, wt, scale, out);
}